// Round 1
// 2249.679 us; speedup vs baseline: 1.2885x; 1.2885x over previous
//
#include <hip/hip_runtime.h>
#include <hip/hip_bf16.h>

// LSTM DynamicRNN: B=128, T=512, D=256, H=512.
// Persistent-weights cooperative kernel, 128 blocks (2 batch-tiles x 64
// col-tiles). Round 4: the two-level counting barrier (sub + master atomic
// RMW chain + centralized poll + block broadcast) is replaced by
// per-producer data flags: each block publishes flags[bt*64+ct]=t+1 after
// its h-slice is ACKed; every wave independently polls the 64 producer
// flags of its batch tile (lane-parallel load + __all). h is stored
// directly from the gates phase (coalesced global_store_short sc0 sc1,
// no LDS staging) and loaded as 16x dwordx4 sc0 sc1 with staged
// vmcnt(8)/vmcnt(0) waits + dual accumulators so the load tail overlaps
// the first 8 MFMAs.

#define B_   128
#define T_   512
#define D_   256
#define H_   512
#define G4_  2048   // 4*H
#define NBLK 128
#define KH   16     // h-part k-steps (K=512)
#define KX   8      // x-part k-steps (K=256)
#define XROW 264    // 256 + 8 pad (shorts) per staged x row

typedef __attribute__((ext_vector_type(8))) short short8;
typedef __attribute__((ext_vector_type(4))) short short4v;
typedef __attribute__((ext_vector_type(4))) float float4v;
typedef __attribute__((ext_vector_type(4))) int   int4v;

__device__ inline unsigned short f2bf_bits(float f) {
    union { float f; unsigned u; } v; v.f = f;
    unsigned r = (v.u + 0x7FFFu + ((v.u >> 16) & 1u)) >> 16;
    return (unsigned short)r;
}

__device__ inline float sigmoid_fast(float x) {
    return 1.f / (1.f + __expf(-x));
}

__device__ inline float tanh_fast(float x) {
    float a = fabsf(x);
    float e = __expf(-2.f * a);
    float r = (1.f - e) / (1.f + e);
    return copysignf(r, x);
}

__device__ inline short4v pack_bf4(float4v v) {
    short4v o;
    o[0] = (short)f2bf_bits(v[0]);
    o[1] = (short)f2bf_bits(v[1]);
    o[2] = (short)f2bf_bits(v[2]);
    o[3] = (short)f2bf_bits(v[3]);
    return o;
}

union HAu { int4v i4; short8 s8; };

__global__ __launch_bounds__(512, 2) void lstm_persistent(
    const float* __restrict__ x, const float* __restrict__ Wx,
    const float* __restrict__ Wh, const float* __restrict__ bias,
    float* __restrict__ out, unsigned short* __restrict__ hbuf,
    unsigned int* __restrict__ flags)
{
    const int tid  = threadIdx.x;
    const int lane = tid & 63;
    const int wave = tid >> 6;      // 8 waves
    const int ms   = wave & 3;      // M-strip (16 rows) within 64-batch tile
    const int nt   = wave >> 2;     // N-tile (16 cols) within 32 cols
    const int ct   = blockIdx.x & 63;   // column tile: hidden units ct*8..+7
    const int bt   = blockIdx.x >> 6;   // batch tile: batches bt*64..+63
    const int jh0  = ct * 8;

    __shared__ float zls[64 * 33];          // z tile, padded
    __shared__ float cls[64 * 8];           // c state
    __shared__ float bls[32];               // bias slice
    __shared__ unsigned short xls[2][64 * XROW];  // double-buffered x_t (bf16)

    for (int i = tid; i < 64 * 8; i += 512) cls[i] = 0.f;
    if (tid < 32) bls[tid] = bias[(tid >> 3) * 512 + jh0 + (tid & 7)];

    // ---- register-resident weight B-frags: ks 0..7 = Wx, ks 8..23 = Wh ----
    const int l15 = lane & 15;
    const int l4  = lane >> 4;
    const int ncol = nt * 16 + l15;
    const int col  = (ncol >> 3) * 512 + jh0 + (ncol & 7);
    short8 wfrag[KX + KH];
#pragma unroll
    for (int ks = 0; ks < KX + KH; ++ks) {
        short8 w;
#pragma unroll
        for (int j = 0; j < 8; ++j) {
            int k = ks * 32 + l4 * 8 + j;
            float v = (k < D_) ? Wx[(size_t)k * G4_ + col]
                               : Wh[(size_t)(k - D_) * G4_ + col];
            w[j] = (short)f2bf_bits(v);
        }
        wfrag[ks] = w;
    }

    // x staging mapping: 16 row-groups of 32 lanes, 512B-contiguous chunks
    const int srow = tid >> 5;          // 0..15
    const int scol = (tid & 31) * 4;    // 0,4,..,124
    const float* xbase = x + (size_t)(bt * 64) * (T_ * D_);

    // A-frag row (h and x): m = ms*16 + l15
    const int mrow = ms * 16 + l15;
    const int gb_a = bt * 64 + mrow;

    // gate-phase mapping
    const int bl = tid >> 3, ug = tid & 7;
    const int gb_g = bt * 64 + bl;

    unsigned int* myflag = flags + bt * 64 + lane;

    // ---- prologue: stage x_0, x-part acc for t=0, prefetch x_1 (packed) ----
    short4v rxp[8];
#pragma unroll
    for (int r = 0; r < 4; ++r) {
        const float* xp = xbase + (size_t)(r * 16 + srow) * (T_ * D_);
        int row = r * 16 + srow;
        *(short4v*)(&xls[0][row * XROW + scol]) =
            pack_bf4(*(const float4v*)(xp + scol));
        *(short4v*)(&xls[0][row * XROW + scol + 128]) =
            pack_bf4(*(const float4v*)(xp + scol + 128));
    }
    __syncthreads();
    float4v accx = {0.f, 0.f, 0.f, 0.f};
#pragma unroll
    for (int ks = 0; ks < KX; ++ks) {
        short8 a = *(const short8*)(&xls[0][mrow * XROW + ks * 32 + l4 * 8]);
        accx = __builtin_amdgcn_mfma_f32_16x16x32_bf16(a, wfrag[ks], accx, 0, 0, 0);
    }
#pragma unroll
    for (int r = 0; r < 4; ++r) {
        const float* xp = xbase + (size_t)(r * 16 + srow) * (T_ * D_) + D_;
        rxp[r * 2]     = pack_bf4(*(const float4v*)(xp + scol));
        rxp[r * 2 + 1] = pack_bf4(*(const float4v*)(xp + scol + 128));
    }

    int cur = 0;
    for (int t = 0; t < T_; ++t) {
        // ---- (A) commit prefetched x_{t+1} into the other LDS buffer ----
        // (last read of this buffer was 2 steps ago, separated by 2 barriers)
        if (t + 1 < T_) {
            unsigned short* xb = xls[(t + 1) & 1];
#pragma unroll
            for (int r = 0; r < 4; ++r) {
                int row = r * 16 + srow;
                *(short4v*)(xb + row * XROW + scol)       = rxp[r * 2];
                *(short4v*)(xb + row * XROW + scol + 128) = rxp[r * 2 + 1];
            }
        }

        // ---- (B) per-wave poll: all 64 producers of this bt at step >= t ----
        if (t) {
            unsigned tgt = (unsigned)t;
            while (true) {
                unsigned f = __hip_atomic_load(myflag, __ATOMIC_RELAXED,
                                               __HIP_MEMORY_SCOPE_AGENT);
                if (__all((int)(f >= tgt))) break;
            }
        }

        // ---- (C) coherent h_t loads: 16 x dwordx4, issued back-to-back ----
        HAu ha[KH];
        {
            const unsigned short* hb0 =
                hbuf + ((size_t)(cur * 64 + l4) * 128 + gb_a) * 8;
#pragma unroll
            for (int ks = 0; ks < KH; ++ks) {
                const unsigned short* ap = hb0 + (size_t)ks * (4 * 128 * 8);
                asm volatile("global_load_dwordx4 %0, %1, off sc0 sc1"
                             : "=v"(ha[ks].i4) : "v"(ap));
            }
        }

        // ---- (D) h-part MFMAs, 2 phases, dual accumulators ----
        float4v a0 = accx;                    // carries the x-part
        float4v a1 = {0.f, 0.f, 0.f, 0.f};
        asm volatile("s_waitcnt vmcnt(8)" ::: "memory");   // 8 oldest done
        __builtin_amdgcn_sched_barrier(0);
#pragma unroll
        for (int ks = 0; ks < 8; ++ks)
            a0 = __builtin_amdgcn_mfma_f32_16x16x32_bf16(
                     ha[ks].s8, wfrag[KX + ks], a0, 0, 0, 0);
        asm volatile("s_waitcnt vmcnt(0)" ::: "memory");
        __builtin_amdgcn_sched_barrier(0);
#pragma unroll
        for (int ks = 8; ks < KH; ++ks)
            a1 = __builtin_amdgcn_mfma_f32_16x16x32_bf16(
                     ha[ks].s8, wfrag[KX + ks], a1, 0, 0, 0);
        // D layout: D[row=(lane>>4)*4+r][col=lane&15]
#pragma unroll
        for (int r = 0; r < 4; ++r) {
            int row = ms * 16 + l4 * 4 + r;
            zls[row * 33 + nt * 16 + l15] = a0[r] + a1[r];
        }
        __syncthreads();

        // ---- (F) gates + direct coherent h store (coalesced shorts) ----
        {
            float zi = zls[bl * 33 + ug]      + bls[ug];
            float zf = zls[bl * 33 + 8 + ug]  + bls[8 + ug];
            float zg = zls[bl * 33 + 16 + ug] + bls[16 + ug];
            float zo = zls[bl * 33 + 24 + ug] + bls[24 + ug];
            float ig = sigmoid_fast(zi);
            float fg = sigmoid_fast(zf);
            float gg = tanh_fast(zg);
            float og = sigmoid_fast(zo);
            float cold = cls[bl * 8 + ug];
            float cnew = fg * cold + ig * gg;
            float hnew = og * tanh_fast(cnew);
            cls[bl * 8 + ug] = cnew;
            unsigned hv = (unsigned)f2bf_bits(hnew);
            unsigned short* hp = hbuf
                + ((size_t)(((t + 1) & 1) * 64 + ct) * 128 + gb_g) * 8 + ug;
            asm volatile("global_store_short %0, %1, off sc0 sc1"
                         :: "v"(hp), "v"(hv) : "memory");
            out[(size_t)gb_g * (T_ * H_) + (size_t)t * H_ + jh0 + ug] = hnew;
            if (t == T_ - 1) {
                const size_t BTH = (size_t)B_ * T_ * H_;
                out[BTH + (size_t)gb_g * H_ + jh0 + ug] = hnew;
                out[BTH + (size_t)B_ * H_ + (size_t)gb_g * H_ + jh0 + ug] = cnew;
            }
        }
        asm volatile("s_waitcnt vmcnt(0)" ::: "memory");   // h-slice ACKed
        __syncthreads();                                   // all waves stored

        // ---- (G) publish: one relaxed agent store, no RMW chain ----
        if (tid == 0)
            __hip_atomic_store(flags + bt * 64 + ct, (unsigned)(t + 1),
                               __ATOMIC_RELAXED, __HIP_MEMORY_SCOPE_AGENT);

        // ---- (H) off-path window: x-part MFMAs for t+1, prefetch x_{t+2} ----
        float4v nacc = {0.f, 0.f, 0.f, 0.f};
        if (t + 1 < T_) {
            const unsigned short* xb = xls[(t + 1) & 1];
#pragma unroll
            for (int ks = 0; ks < KX; ++ks) {
                short8 a = *(const short8*)(xb + mrow * XROW + ks * 32 + l4 * 8);
                nacc = __builtin_amdgcn_mfma_f32_16x16x32_bf16(
                           a, wfrag[ks], nacc, 0, 0, 0);
            }
            if (t + 2 < T_) {
#pragma unroll
                for (int r = 0; r < 4; ++r) {
                    const float* xp = xbase + (size_t)(r * 16 + srow) * (T_ * D_)
                                    + (size_t)(t + 2) * D_;
                    rxp[r * 2]     = pack_bf4(*(const float4v*)(xp + scol));
                    rxp[r * 2 + 1] = pack_bf4(*(const float4v*)(xp + scol + 128));
                }
            }
        }
        accx = nacc;
        cur ^= 1;
    }
}

extern "C" void kernel_launch(void* const* d_in, const int* in_sizes, int n_in,
                              void* d_out, int out_size, void* d_ws, size_t ws_size,
                              hipStream_t stream) {
    const float* x    = (const float*)d_in[0];
    const float* Wx   = (const float*)d_in[1];
    const float* Wh   = (const float*)d_in[2];
    const float* bias = (const float*)d_in[3];
    float* out = (float*)d_out;

    unsigned short* hbuf = (unsigned short*)d_ws;  // 2x[64][128][8] bf16
    const size_t hbuf_bytes = (size_t)2 * 64 * 128 * 8 * sizeof(unsigned short);
    unsigned int* flags = (unsigned int*)((char*)d_ws + hbuf_bytes);  // 128 u32

    hipMemsetAsync(d_ws, 0, hbuf_bytes + 1024, stream);

    lstm_persistent<<<dim3(NBLK), dim3(512), 0, stream>>>(
        x, Wx, Wh, bias, out, hbuf, flags);
}